// Round 17
// baseline (248.219 us; speedup 1.0000x reference)
//
#include <hip/hip_runtime.h>
#include <cfloat>

#define LATENT 256
#define NV 8192
#define NROWS 16384   // B*H*W
#define HW 1024
#define CHW (LATENT * HW)         // 262144
#define PLANE 4194304             // B*C*H*W
#define IDX_OFF (2 * PLANE)       // 8388608
#define LOSS_OFF (IDX_OFF + NROWS)
#define MARGIN_S 6e-4f            // worst-case containment needs >= ~4.4e-4
#define CAP 2048                  // candidate-list capacity (typ. ~100 used per 32 rows)

typedef __bf16 bf16x8 __attribute__((ext_vector_type(8)));
typedef float f32x4 __attribute__((ext_vector_type(4)));

__device__ inline unsigned short f2bf(float f) {  // RNE f32->bf16 (finite inputs)
  unsigned u = __builtin_bit_cast(unsigned, f);
  u = u + 0x7FFFu + ((u >> 16) & 1u);
  return (unsigned short)(u >> 16);
}
__device__ inline float bf2f(unsigned short h) {
  return __builtin_bit_cast(float, (unsigned)h << 16);
}

// ---------------- fused prep: ek -> ek_hi (bf16 [k][c]); x -> x_hi (bf16 [row][c]) ----------------
__global__ __launch_bounds__(256) void prep_kernel(const float* __restrict__ ek,
                                                   const float* __restrict__ x,
                                                   unsigned short* __restrict__ ek_hi,
                                                   unsigned short* __restrict__ x_hi) {
  __shared__ float tile[64][68];
  const int t = threadIdx.x;
  if (blockIdx.x < 1024) {   // ek: pure elementwise bf16 cast
    int i = ((int)blockIdx.x * 256 + t) << 3;
    float4 a = *(const float4*)(ek + i);
    float4 b = *(const float4*)(ek + i + 4);
    ushort4 h0, h1;
    h0.x = f2bf(a.x); h0.y = f2bf(a.y); h0.z = f2bf(a.z); h0.w = f2bf(a.w);
    h1.x = f2bf(b.x); h1.y = f2bf(b.y); h1.z = f2bf(b.z); h1.w = f2bf(b.w);
    *(ushort4*)(ek_hi + i) = h0;
    *(ushort4*)(ek_hi + i + 4) = h1;
    return;
  }
  const int bid = blockIdx.x - 1024;   // x: transpose + cast
  const int b = bid >> 6;
  const int c0 = ((bid >> 4) & 3) << 6;
  const int hw0 = (bid & 15) << 6;
  #pragma unroll
  for (int p = 0; p < 4; ++p) {
    int id = (p << 8) + t;
    int r = id >> 4;            // c-local
    int h4 = (id & 15) << 2;    // hw offset
    float4 v = *(const float4*)(x + (size_t)b * CHW + (size_t)(c0 + r) * HW + hw0 + h4);
    *(float4*)&tile[r][h4] = v;
  }
  __syncthreads();
  #pragma unroll
  for (int p = 0; p < 4; ++p) {
    int id = (p << 8) + t;
    int rh = id >> 4;           // hw-local
    int c4 = (id & 15) << 2;    // c offset
    ushort4 h;
    h.x = f2bf(tile[c4][rh]);     h.y = f2bf(tile[c4 + 1][rh]);
    h.z = f2bf(tile[c4 + 2][rh]); h.w = f2bf(tile[c4 + 3][rh]);
    *(ushort4*)(x_hi + (size_t)((b << 10) + hw0 + rh) * LATENT + c0 + c4) = h;
  }
}

// ---------------- phase A: bf16 MFMA S=x.ek^T; per-(row,16-code-subtile) ----------------
// FINAL (verified r9/13/16, 143.5us; all schedule surgeries measured worse).
__global__ __launch_bounds__(256, 4) void phaseA(const unsigned short* __restrict__ ek_hi,
                                                 const unsigned short* __restrict__ x_hi,
                                                 unsigned* __restrict__ smax) {
  __shared__ unsigned short As[2][4][128][8];  // [buf][q][code][8 elems] (8KB/buf)
  __shared__ unsigned short Bs[2][4][128][8];  // [buf][q][row ][8 elems]
  const int t = threadIdx.x;
  const int mt = blockIdx.x & 63;
  const int panel = blockIdx.x >> 6;
  const int m0 = mt << 7, r0 = panel << 7;
  const int sside = t >> 7;        // 0: A(ek), 1: B(x)
  const int sr = t & 127;
  const unsigned short* src = sside ? x_hi + (size_t)(r0 + sr) * LATENT
                                    : ek_hi + (size_t)(m0 + sr) * LATENT;
  uint4 reg[4];
  #pragma unroll
  for (int q = 0; q < 4; ++q) reg[q] = *(const uint4*)(src + (q << 3));
  {
    unsigned short (*dst)[128][8] = sside ? Bs[0] : As[0];
    #pragma unroll
    for (int q = 0; q < 4; ++q) *(uint4*)&dst[q][sr][0] = reg[q];
  }
  const int w = t >> 6, l = t & 63;
  const int lm = l & 15, q4 = l >> 4;
  const int mw = (w & 1) << 6;
  const int nw = (w >> 1) << 6;
  f32x4 acc[4][4];
  #pragma unroll
  for (int ms = 0; ms < 4; ++ms)
    #pragma unroll
    for (int ns = 0; ns < 4; ++ns) acc[ms][ns] = (f32x4){0.f, 0.f, 0.f, 0.f};
  for (int kc = 0; kc < 8; ++kc) {
    const int buf = kc & 1;
    __syncthreads();
    if (kc < 7) {
      #pragma unroll
      for (int q = 0; q < 4; ++q)
        reg[q] = *(const uint4*)(src + ((kc + 1) << 5) + (q << 3));
    }
    bf16x8 a[4], b[4];
    #pragma unroll
    for (int ms = 0; ms < 4; ++ms)
      a[ms] = *(const bf16x8*)&As[buf][q4][mw + (ms << 4) + lm][0];
    #pragma unroll
    for (int ns = 0; ns < 4; ++ns)
      b[ns] = *(const bf16x8*)&Bs[buf][q4][nw + (ns << 4) + lm][0];
    #pragma unroll
    for (int ms = 0; ms < 4; ++ms)
      #pragma unroll
      for (int ns = 0; ns < 4; ++ns)
        acc[ms][ns] = __builtin_amdgcn_mfma_f32_16x16x32_bf16(a[ms], b[ns], acc[ms][ns], 0, 0, 0);
    if (kc < 7) {
      unsigned short (*dst)[128][8] = sside ? Bs[buf ^ 1] : As[buf ^ 1];
      #pragma unroll
      for (int q = 0; q < 4; ++q) *(uint4*)&dst[q][sr][0] = reg[q];
    }
  }
  unsigned* stg = (unsigned*)&As[0][0][0][0];
  const int lbase = (l >> 4) << 2;
  #pragma unroll
  for (int ms = 0; ms < 4; ++ms) {
    #pragma unroll
    for (int ns = 0; ns < 4; ++ns) {
      f32x4 v4 = acc[ms][ns];
      float mx = fmaxf(fmaxf(v4[0], v4[1]), fmaxf(v4[2], v4[3]));
      mx = fmaxf(mx, __shfl_xor(mx, 16, 64));
      mx = fmaxf(mx, __shfl_xor(mx, 32, 64));
      float th = mx - MARGIN_S;
      unsigned mk = 0;
      #pragma unroll
      for (int r = 0; r < 4; ++r) if (v4[r] >= th) mk |= 1u << (lbase + r);
      mk |= (unsigned)__shfl_xor((int)mk, 16, 64);
      mk |= (unsigned)__shfl_xor((int)mk, 32, 64);
      if (l < 16) {
        int sloc = ((w & 1) << 2) + ms;
        int rloc = nw + (ns << 4) + l;
        stg[(sloc << 7) + rloc] = (unsigned)f2bf(mx) | (mk << 16);
      }
    }
  }
  __syncthreads();
  #pragma unroll
  for (int p = 0; p < 4; ++p) {
    int wid = (p << 8) + t;
    int sloc = wid >> 7;
    int rloc = wid & 127;
    smax[(size_t)((mt << 3) + sloc) * NROWS + r0 + rloc] = stg[wid];
  }
}

// ---------------- phase B: candidate-parallel exact recompute ----------------
__global__ __launch_bounds__(256) void phaseB(const float* __restrict__ x,
                                              const float* __restrict__ ek,
                                              const unsigned* __restrict__ smax,
                                              int* __restrict__ idxw,
                                              float* __restrict__ out) {
  __shared__ float xs[32][257];
  __shared__ float pmax[32][8];
  __shared__ float thrs[32];
  __shared__ float Xs[32];
  __shared__ unsigned long long best[32];
  __shared__ unsigned list[CAP];
  __shared__ int cnt;
  const int t = threadIdx.x;
  const int row0 = blockIdx.x << 5;
  const int b = row0 >> 10;
  const int hw0 = row0 & 1023;
  if (t == 0) cnt = 0;
  if (t < 32) best[t] = ~0ull;
  #pragma unroll
  for (int p = 0; p < 8; ++p) {
    int id = (p << 8) + t;
    int c = id >> 3;
    int r4 = (id & 7) << 2;
    float4 v = *(const float4*)(x + (size_t)b * CHW + (size_t)c * HW + hw0 + r4);
    xs[r4 + 0][c] = v.x; xs[r4 + 1][c] = v.y; xs[r4 + 2][c] = v.z; xs[r4 + 3][c] = v.w;
  }
  {
    const int r = t >> 3, q = t & 7;
    float m = -FLT_MAX;
    #pragma unroll 8
    for (int i = 0; i < 64; ++i) {
      unsigned wd = smax[(size_t)((i << 3) + q) * NROWS + row0 + r];
      m = fmaxf(m, bf2f((unsigned short)(wd & 0xffffu)));
    }
    pmax[r][q] = m;
  }
  __syncthreads();
  if (t < 32) {
    float m = pmax[t][0];
    #pragma unroll
    for (int q = 1; q < 8; ++q) m = fmaxf(m, pmax[t][q]);
    thrs[t] = m - MARGIN_S;
    double s = 0.0;
    for (int c = 0; c < 256; ++c) {
      double v = (double)xs[t][c];
      s = fma(v, v, s);
    }
    Xs[t] = (float)s;
  }
  __syncthreads();
  {
    const int r = t >> 3, q = t & 7;
    const float thr = thrs[r];
    for (int i = 0; i < 64; ++i) {
      unsigned wd = smax[(size_t)((i << 3) + q) * NROWS + row0 + r];
      if (bf2f((unsigned short)(wd & 0xffffu)) >= thr) {
        unsigned mk = wd >> 16;
        int sidx = (i << 3) + q;
        while (mk) {
          int bit = __builtin_ctz(mk);
          mk &= mk - 1;
          int k = (sidx << 4) + bit;
          int slot = atomicAdd(&cnt, 1);
          if (slot < CAP) {
            list[slot] = ((unsigned)r << 13) | (unsigned)k;
          } else {
            const float* xr = &xs[r][0];
            const float* ep = ek + (size_t)k * LATENT;
            float f = 0.f;
            #pragma unroll 8
            for (int c = 0; c < 256; ++c) f = fmaf(xr[c], ep[c], f);
            float d = fmaf(-2.f, f, Xs[r]);
            unsigned u = __builtin_bit_cast(unsigned, d);
            u ^= (u >> 31) ? 0xFFFFFFFFu : 0x80000000u;
            atomicMin(&best[r], ((unsigned long long)u << 32) | (unsigned)k);
          }
        }
      }
    }
  }
  __syncthreads();
  const int n = cnt < CAP ? cnt : CAP;
  for (int i = t; i < n; i += 256) {
    unsigned enc = list[i];
    int r = enc >> 13;
    int k = enc & 0x1fff;
    const float* xr = &xs[r][0];
    const float* ep = ek + (size_t)k * LATENT;
    float f = 0.f;
    #pragma unroll 8
    for (int c = 0; c < 256; ++c) f = fmaf(xr[c], ep[c], f);
    float d = fmaf(-2.f, f, Xs[r]);
    unsigned u = __builtin_bit_cast(unsigned, d);
    u ^= (u >> 31) ? 0xFFFFFFFFu : 0x80000000u;
    atomicMin(&best[r], ((unsigned long long)u << 32) | (unsigned)k);
  }
  __syncthreads();
  if (t < 32) {
    int k = (int)(best[t] & 0xFFFFFFFFu);
    idxw[row0 + t] = k;
    out[IDX_OFF + row0 + t] = (float)k;
  }
}

// ---------------- out: gather-GEMM + transpose epilogue + loss partials ----------------
// Round-17: 512 blocks x 32 rows (was 256 x 64 = exactly 1 block/CU with ~40
// barriers and nothing to overlap them; 2 blocks/CU lets one block's compute
// hide the other's barrier stalls — the r7->r9 lesson applied here).
// Per-element xq chain (cc-ascending, c-ascending fmaf) unchanged -> outputs
// 0/1 bit-identical; loss partials regroup (fp32 reassoc, ~1e-7 rel).
__global__ __launch_bounds__(256) void out_kernel(
    const float* __restrict__ ek, const float* __restrict__ ev,
    const float* __restrict__ x, const int* __restrict__ idxw,
    float* __restrict__ out, float* __restrict__ bsum) {
  __shared__ float As[32][36];    // gathered ek chunk [c][row 0..32]; later xL[32][36]
  __shared__ float Vs[32][260];   // V chunk [c][j]; later stL/xqL
  __shared__ int idx_s[32];
  __shared__ float red[256];
  const int t = threadIdx.x;
  const int blk = blockIdx.x;
  const int i0 = blk << 5;        // 32 rows
  if (t < 32) idx_s[t] = idxw[i0 + t];
  const int ty = t >> 5;  // 0..7 -> rows ty*4 (of 32)
  const int tx = t & 31;  // j = tx*8 (of 256)
  float acc[4][8];
  #pragma unroll
  for (int r = 0; r < 4; ++r)
    #pragma unroll
    for (int j = 0; j < 8; ++j) acc[r][j] = 0.f;
  for (int cc = 0; cc < 8; ++cc) {
    __syncthreads();
    {  // gather A chunk: 32 rows x 32 c, transposed (one float4 per thread)
      int r = t >> 3, cl = (t & 7) << 2;
      const float* eb = ek + (size_t)idx_s[r] * LATENT + (cc << 5) + cl;
      float4 v0 = *(const float4*)eb;
      As[cl + 0][r] = v0.x; As[cl + 1][r] = v0.y;
      As[cl + 2][r] = v0.z; As[cl + 3][r] = v0.w;
    }
    {  // stage V chunk: 32 c x 256 j
      int c = t >> 3, jb = (t & 7) << 5;
      const float* vb = ev + (size_t)((cc << 5) + c) * LATENT + jb;
      float4* dst = (float4*)&Vs[c][jb];
      #pragma unroll
      for (int q = 0; q < 8; ++q) dst[q] = *(const float4*)(vb + 4 * q);
    }
    __syncthreads();
    #pragma unroll
    for (int c = 0; c < 32; ++c) {
      float a[4], bv[8];
      *(float4*)&a[0] = *(const float4*)&As[c][ty << 2];
      *(float4*)&bv[0] = *(const float4*)&Vs[c][tx << 3];
      *(float4*)&bv[4] = *(const float4*)&Vs[c][(tx << 3) + 4];
      #pragma unroll
      for (int r = 0; r < 4; ++r)
        #pragma unroll
        for (int j = 0; j < 8; ++j) acc[r][j] = fmaf(a[r], bv[j], acc[r][j]);
    }
  }
  __syncthreads();   // GEMM LDS reads done before epilogue reuses As/Vs
  // epilogue via LDS: iteration j handles channels {ch*8+j}, 32 rows each
  const int bb = i0 >> 10;
  const int hwb = i0 & 1023;      // multiple of 32
  float* xL  = &As[0][0];         // [32][36]
  float* stL = &Vs[0][0];         // [32][36]
  float* xqL = stL + 32 * 36;     // [32][36] (Vs holds 32*260 >= 2*32*36)
  const int ch = t >> 3;          // 0..31
  const int part = t & 7;         // 0..7 -> 4 floats each (32 hw)
  float lsum = 0.f;
  for (int j = 0; j < 8; ++j) {
    {  // P1: coalesced x load -> xL (channel ch*8+j -> LDS row ch)
      const float* xp = x + (size_t)bb * CHW + (size_t)((ch << 3) + j) * HW + hwb + (part << 2);
      *(float4*)&xL[ch * 36 + (part << 2)] = *(const float4*)xp;
    }
    __syncthreads();
    {  // P2: thread owns rows ty*4+r, col tx*8+j -> channel-local = tx
      #pragma unroll
      for (int r = 0; r < 4; ++r) {
        float xq = acc[r][j];
        float xt = xL[tx * 36 + (ty << 2) + r];
        float tmp = xq - xt;
        lsum = fmaf(tmp, tmp, lsum);
        stL[tx * 36 + (ty << 2) + r] = xt + tmp;
        xqL[tx * 36 + (ty << 2) + r] = xq;
      }
    }
    __syncthreads();
    {  // P3: coalesced stores (128B runs per channel)
      float* o0 = out + (size_t)bb * CHW + (size_t)((ch << 3) + j) * HW + hwb + (part << 2);
      float* o1 = o0 + PLANE;
      *(float4*)o0 = *(const float4*)&stL[ch * 36 + (part << 2)];
      *(float4*)o1 = *(const float4*)&xqL[ch * 36 + (part << 2)];
    }
    __syncthreads();
  }
  red[t] = lsum;
  __syncthreads();
  for (int s = 128; s > 0; s >>= 1) {
    if (t < s) red[t] += red[t + s];
    __syncthreads();
  }
  if (t == 0) bsum[blk] = red[0];
}

// ---------------- loss (512 partials) ----------------
__global__ __launch_bounds__(256) void fin_kernel(const float* __restrict__ bsum,
                                                  float* __restrict__ out) {
  __shared__ float red[256];
  int t = threadIdx.x;
  red[t] = bsum[t] + bsum[t + 256];
  __syncthreads();
  for (int s = 128; s > 0; s >>= 1) {
    if (t < s) red[t] += red[t + s];
    __syncthreads();
  }
  if (t == 0) {
    float m = red[0] / (float)PLANE;
    out[LOSS_OFF] = m + 0.25f * m;
  }
}

extern "C" void kernel_launch(void* const* d_in, const int* in_sizes, int n_in,
                              void* d_out, int out_size, void* d_ws, size_t ws_size,
                              hipStream_t stream) {
  const float* x = (const float*)d_in[0];
  const float* ek = (const float*)d_in[1];
  const float* ev = (const float*)d_in[2];
  float* out = (float*)d_out;
  char* base = (char*)d_ws;
  unsigned short* ek_hi = (unsigned short*)(base);             //  4.0 MB
  unsigned short* x_hi  = (unsigned short*)(base + 4194304);   //  8.0 MB
  int*            idxw  = (int*)(base + 12582912);             // 64 KB
  float*          bsum  = (float*)(base + 12648448);           //  2 KB (512 partials)
  // smax (512 sidx x 16384 rows uints = 32 MB) lives in d_out's two output
  // planes, which out_kernel fully overwrites afterwards (same-stream ordering).
  unsigned* smax = (unsigned*)d_out;

  prep_kernel<<<2048, 256, 0, stream>>>(ek, x, ek_hi, x_hi);
  phaseA<<<8192, 256, 0, stream>>>(ek_hi, x_hi, smax);
  phaseB<<<512, 256, 0, stream>>>(x, ek, smax, idxw, out);
  out_kernel<<<512, 256, 0, stream>>>(ek, ev, x, idxw, out, bsum);
  fin_kernel<<<1, 256, 0, stream>>>(bsum, out);
}

// Round 18
// 244.714 us; speedup vs baseline: 1.0143x; 1.0143x over previous
//
#include <hip/hip_runtime.h>
#include <cfloat>

#define LATENT 256
#define NV 8192
#define NROWS 16384   // B*H*W
#define HW 1024
#define CHW (LATENT * HW)         // 262144
#define PLANE 4194304             // B*C*H*W
#define IDX_OFF (2 * PLANE)       // 8388608
#define LOSS_OFF (IDX_OFF + NROWS)
#define MARGIN_S 6e-4f            // worst-case containment needs >= ~4.4e-4
#define CAP 2048                  // candidate-list capacity (typ. ~100 used per 32 rows)

typedef __bf16 bf16x8 __attribute__((ext_vector_type(8)));
typedef float f32x4 __attribute__((ext_vector_type(4)));

__device__ inline unsigned short f2bf(float f) {  // RNE f32->bf16 (finite inputs)
  unsigned u = __builtin_bit_cast(unsigned, f);
  u = u + 0x7FFFu + ((u >> 16) & 1u);
  return (unsigned short)(u >> 16);
}
__device__ inline float bf2f(unsigned short h) {
  return __builtin_bit_cast(float, (unsigned)h << 16);
}

// ---------------- fused prep: ek -> ek_hi (bf16 [k][c]); x -> x_hi (bf16 [row][c]) ----------------
__global__ __launch_bounds__(256) void prep_kernel(const float* __restrict__ ek,
                                                   const float* __restrict__ x,
                                                   unsigned short* __restrict__ ek_hi,
                                                   unsigned short* __restrict__ x_hi) {
  __shared__ float tile[64][68];
  const int t = threadIdx.x;
  if (blockIdx.x < 1024) {   // ek: pure elementwise bf16 cast
    int i = ((int)blockIdx.x * 256 + t) << 3;
    float4 a = *(const float4*)(ek + i);
    float4 b = *(const float4*)(ek + i + 4);
    ushort4 h0, h1;
    h0.x = f2bf(a.x); h0.y = f2bf(a.y); h0.z = f2bf(a.z); h0.w = f2bf(a.w);
    h1.x = f2bf(b.x); h1.y = f2bf(b.y); h1.z = f2bf(b.z); h1.w = f2bf(b.w);
    *(ushort4*)(ek_hi + i) = h0;
    *(ushort4*)(ek_hi + i + 4) = h1;
    return;
  }
  const int bid = blockIdx.x - 1024;   // x: transpose + cast
  const int b = bid >> 6;
  const int c0 = ((bid >> 4) & 3) << 6;
  const int hw0 = (bid & 15) << 6;
  #pragma unroll
  for (int p = 0; p < 4; ++p) {
    int id = (p << 8) + t;
    int r = id >> 4;            // c-local
    int h4 = (id & 15) << 2;    // hw offset
    float4 v = *(const float4*)(x + (size_t)b * CHW + (size_t)(c0 + r) * HW + hw0 + h4);
    *(float4*)&tile[r][h4] = v;
  }
  __syncthreads();
  #pragma unroll
  for (int p = 0; p < 4; ++p) {
    int id = (p << 8) + t;
    int rh = id >> 4;           // hw-local
    int c4 = (id & 15) << 2;    // c offset
    ushort4 h;
    h.x = f2bf(tile[c4][rh]);     h.y = f2bf(tile[c4 + 1][rh]);
    h.z = f2bf(tile[c4 + 2][rh]); h.w = f2bf(tile[c4 + 3][rh]);
    *(ushort4*)(x_hi + (size_t)((b << 10) + hw0 + rh) * LATENT + c0 + c4) = h;
  }
}

// ---------------- phase A: bf16 MFMA S=x.ek^T; per-(row,16-code-subtile) ----------------
// FINAL (verified r9/13/16, 143.5us). 128x128 tile, 4 waves, BK=32 dbuf,
// q-major LDS (conflict-free), 4 blocks/CU; per kc: barrier -> issue loads ->
// frags/MFMA -> ds_write. All schedule surgeries measured worse on this
// HW/compiler (gload_lds +20%; 8-wave spill +290%; asm-barrier prefetch +125%).
__global__ __launch_bounds__(256, 4) void phaseA(const unsigned short* __restrict__ ek_hi,
                                                 const unsigned short* __restrict__ x_hi,
                                                 unsigned* __restrict__ smax) {
  __shared__ unsigned short As[2][4][128][8];  // [buf][q][code][8 elems] (8KB/buf)
  __shared__ unsigned short Bs[2][4][128][8];  // [buf][q][row ][8 elems]
  const int t = threadIdx.x;
  const int mt = blockIdx.x & 63;
  const int panel = blockIdx.x >> 6;
  const int m0 = mt << 7, r0 = panel << 7;
  const int sside = t >> 7;        // 0: A(ek), 1: B(x)
  const int sr = t & 127;
  const unsigned short* src = sside ? x_hi + (size_t)(r0 + sr) * LATENT
                                    : ek_hi + (size_t)(m0 + sr) * LATENT;
  uint4 reg[4];
  #pragma unroll
  for (int q = 0; q < 4; ++q) reg[q] = *(const uint4*)(src + (q << 3));
  {
    unsigned short (*dst)[128][8] = sside ? Bs[0] : As[0];
    #pragma unroll
    for (int q = 0; q < 4; ++q) *(uint4*)&dst[q][sr][0] = reg[q];
  }
  const int w = t >> 6, l = t & 63;
  const int lm = l & 15, q4 = l >> 4;
  const int mw = (w & 1) << 6;
  const int nw = (w >> 1) << 6;
  f32x4 acc[4][4];
  #pragma unroll
  for (int ms = 0; ms < 4; ++ms)
    #pragma unroll
    for (int ns = 0; ns < 4; ++ns) acc[ms][ns] = (f32x4){0.f, 0.f, 0.f, 0.f};
  for (int kc = 0; kc < 8; ++kc) {
    const int buf = kc & 1;
    __syncthreads();
    if (kc < 7) {
      #pragma unroll
      for (int q = 0; q < 4; ++q)
        reg[q] = *(const uint4*)(src + ((kc + 1) << 5) + (q << 3));
    }
    bf16x8 a[4], b[4];
    #pragma unroll
    for (int ms = 0; ms < 4; ++ms)
      a[ms] = *(const bf16x8*)&As[buf][q4][mw + (ms << 4) + lm][0];
    #pragma unroll
    for (int ns = 0; ns < 4; ++ns)
      b[ns] = *(const bf16x8*)&Bs[buf][q4][nw + (ns << 4) + lm][0];
    #pragma unroll
    for (int ms = 0; ms < 4; ++ms)
      #pragma unroll
      for (int ns = 0; ns < 4; ++ns)
        acc[ms][ns] = __builtin_amdgcn_mfma_f32_16x16x32_bf16(a[ms], b[ns], acc[ms][ns], 0, 0, 0);
    if (kc < 7) {
      unsigned short (*dst)[128][8] = sside ? Bs[buf ^ 1] : As[buf ^ 1];
      #pragma unroll
      for (int q = 0; q < 4; ++q) *(uint4*)&dst[q][sr][0] = reg[q];
    }
  }
  unsigned* stg = (unsigned*)&As[0][0][0][0];
  const int lbase = (l >> 4) << 2;
  #pragma unroll
  for (int ms = 0; ms < 4; ++ms) {
    #pragma unroll
    for (int ns = 0; ns < 4; ++ns) {
      f32x4 v4 = acc[ms][ns];
      float mx = fmaxf(fmaxf(v4[0], v4[1]), fmaxf(v4[2], v4[3]));
      mx = fmaxf(mx, __shfl_xor(mx, 16, 64));
      mx = fmaxf(mx, __shfl_xor(mx, 32, 64));
      float th = mx - MARGIN_S;
      unsigned mk = 0;
      #pragma unroll
      for (int r = 0; r < 4; ++r) if (v4[r] >= th) mk |= 1u << (lbase + r);
      mk |= (unsigned)__shfl_xor((int)mk, 16, 64);
      mk |= (unsigned)__shfl_xor((int)mk, 32, 64);
      if (l < 16) {
        int sloc = ((w & 1) << 2) + ms;
        int rloc = nw + (ns << 4) + l;
        stg[(sloc << 7) + rloc] = (unsigned)f2bf(mx) | (mk << 16);
      }
    }
  }
  __syncthreads();
  #pragma unroll
  for (int p = 0; p < 4; ++p) {
    int wid = (p << 8) + t;
    int sloc = wid >> 7;
    int rloc = wid & 127;
    smax[(size_t)((mt << 3) + sloc) * NROWS + r0 + rloc] = stg[wid];
  }
}

// ---------------- phase B: candidate-parallel exact recompute ----------------
// 512 blocks x 32 rows. Exact c-ascending fp32 FMA chain, u64 atomicMin on
// (sortable(d)<<32)|k -> lexicographic (d,k) min = first-index ties. smax [sidx][row].
__global__ __launch_bounds__(256) void phaseB(const float* __restrict__ x,
                                              const float* __restrict__ ek,
                                              const unsigned* __restrict__ smax,
                                              int* __restrict__ idxw,
                                              float* __restrict__ out) {
  __shared__ float xs[32][257];
  __shared__ float pmax[32][8];
  __shared__ float thrs[32];
  __shared__ float Xs[32];
  __shared__ unsigned long long best[32];
  __shared__ unsigned list[CAP];
  __shared__ int cnt;
  const int t = threadIdx.x;
  const int row0 = blockIdx.x << 5;
  const int b = row0 >> 10;
  const int hw0 = row0 & 1023;
  if (t == 0) cnt = 0;
  if (t < 32) best[t] = ~0ull;
  #pragma unroll
  for (int p = 0; p < 8; ++p) {
    int id = (p << 8) + t;
    int c = id >> 3;
    int r4 = (id & 7) << 2;
    float4 v = *(const float4*)(x + (size_t)b * CHW + (size_t)c * HW + hw0 + r4);
    xs[r4 + 0][c] = v.x; xs[r4 + 1][c] = v.y; xs[r4 + 2][c] = v.z; xs[r4 + 3][c] = v.w;
  }
  {
    const int r = t >> 3, q = t & 7;
    float m = -FLT_MAX;
    #pragma unroll 8
    for (int i = 0; i < 64; ++i) {
      unsigned wd = smax[(size_t)((i << 3) + q) * NROWS + row0 + r];
      m = fmaxf(m, bf2f((unsigned short)(wd & 0xffffu)));
    }
    pmax[r][q] = m;
  }
  __syncthreads();
  if (t < 32) {
    float m = pmax[t][0];
    #pragma unroll
    for (int q = 1; q < 8; ++q) m = fmaxf(m, pmax[t][q]);
    thrs[t] = m - MARGIN_S;
    double s = 0.0;
    for (int c = 0; c < 256; ++c) {
      double v = (double)xs[t][c];
      s = fma(v, v, s);
    }
    Xs[t] = (float)s;
  }
  __syncthreads();
  {
    const int r = t >> 3, q = t & 7;
    const float thr = thrs[r];
    for (int i = 0; i < 64; ++i) {
      unsigned wd = smax[(size_t)((i << 3) + q) * NROWS + row0 + r];
      if (bf2f((unsigned short)(wd & 0xffffu)) >= thr) {
        unsigned mk = wd >> 16;
        int sidx = (i << 3) + q;
        while (mk) {
          int bit = __builtin_ctz(mk);
          mk &= mk - 1;
          int k = (sidx << 4) + bit;
          int slot = atomicAdd(&cnt, 1);
          if (slot < CAP) {
            list[slot] = ((unsigned)r << 13) | (unsigned)k;
          } else {
            const float* xr = &xs[r][0];
            const float* ep = ek + (size_t)k * LATENT;
            float f = 0.f;
            #pragma unroll 8
            for (int c = 0; c < 256; ++c) f = fmaf(xr[c], ep[c], f);
            float d = fmaf(-2.f, f, Xs[r]);
            unsigned u = __builtin_bit_cast(unsigned, d);
            u ^= (u >> 31) ? 0xFFFFFFFFu : 0x80000000u;
            atomicMin(&best[r], ((unsigned long long)u << 32) | (unsigned)k);
          }
        }
      }
    }
  }
  __syncthreads();
  const int n = cnt < CAP ? cnt : CAP;
  for (int i = t; i < n; i += 256) {
    unsigned enc = list[i];
    int r = enc >> 13;
    int k = enc & 0x1fff;
    const float* xr = &xs[r][0];
    const float* ep = ek + (size_t)k * LATENT;
    float f = 0.f;
    #pragma unroll 8
    for (int c = 0; c < 256; ++c) f = fmaf(xr[c], ep[c], f);
    float d = fmaf(-2.f, f, Xs[r]);
    unsigned u = __builtin_bit_cast(unsigned, d);
    u ^= (u >> 31) ? 0xFFFFFFFFu : 0x80000000u;
    atomicMin(&best[r], ((unsigned long long)u << 32) | (unsigned)k);
  }
  __syncthreads();
  if (t < 32) {
    int k = (int)(best[t] & 0xFFFFFFFFu);
    idxw[row0 + t] = k;
    out[IDX_OFF + row0 + t] = (float)k;
  }
}

// ---------------- out: gather-GEMM + transpose epilogue + loss partials ----------------
// FINAL (= r16-verified 256-block version; r17's 512x32 split measured -1.4%).
__global__ __launch_bounds__(256) void out_kernel(
    const float* __restrict__ ek, const float* __restrict__ ev,
    const float* __restrict__ x, const int* __restrict__ idxw,
    float* __restrict__ out, float* __restrict__ bsum) {
  __shared__ float As[32][68];    // gathered ek chunk [c][row]; later xL[32][68]
  __shared__ float Vs[32][260];   // V chunk [c][j]; later stL/xqL
  __shared__ int idx_s[64];
  __shared__ float red[256];
  const int t = threadIdx.x;
  const int blk = blockIdx.x;
  const int i0 = blk << 6;
  if (t < 64) idx_s[t] = idxw[i0 + t];
  const int ty = t >> 5;  // rows ty*8 (of 64)
  const int tx = t & 31;  // j = tx*8 (of 256)
  float acc[8][8];
  #pragma unroll
  for (int r = 0; r < 8; ++r)
    #pragma unroll
    for (int j = 0; j < 8; ++j) acc[r][j] = 0.f;
  for (int cc = 0; cc < 8; ++cc) {
    __syncthreads();
    {  // gather A chunk: 64 rows x 32 c, transposed
      int r = t >> 2, cl = (t & 3) << 3;
      const float* eb = ek + (size_t)idx_s[r] * LATENT + (cc << 5) + cl;
      float4 v0 = *(const float4*)eb;
      float4 v1 = *(const float4*)(eb + 4);
      As[cl + 0][r] = v0.x; As[cl + 1][r] = v0.y;
      As[cl + 2][r] = v0.z; As[cl + 3][r] = v0.w;
      As[cl + 4][r] = v1.x; As[cl + 5][r] = v1.y;
      As[cl + 6][r] = v1.z; As[cl + 7][r] = v1.w;
    }
    {  // stage V chunk: 32 c x 256 j
      int c = t >> 3, jb = (t & 7) << 5;
      const float* vb = ev + (size_t)((cc << 5) + c) * LATENT + jb;
      float4* dst = (float4*)&Vs[c][jb];
      #pragma unroll
      for (int q = 0; q < 8; ++q) dst[q] = *(const float4*)(vb + 4 * q);
    }
    __syncthreads();
    #pragma unroll
    for (int c = 0; c < 32; ++c) {
      float a[8], bv[8];
      *(float4*)&a[0] = *(const float4*)&As[c][ty << 3];
      *(float4*)&a[4] = *(const float4*)&As[c][(ty << 3) + 4];
      *(float4*)&bv[0] = *(const float4*)&Vs[c][tx << 3];
      *(float4*)&bv[4] = *(const float4*)&Vs[c][(tx << 3) + 4];
      #pragma unroll
      for (int r = 0; r < 8; ++r)
        #pragma unroll
        for (int j = 0; j < 8; ++j) acc[r][j] = fmaf(a[r], bv[j], acc[r][j]);
    }
  }
  __syncthreads();   // GEMM LDS reads done before epilogue reuses As/Vs
  // epilogue via LDS: channels ch*8+j, 64 rows, coalesced 256B runs
  const int bb = i0 >> 10;
  const int hwb = i0 & 1023;
  float* xL  = &As[0][0];          // [32][68]
  float* stL = &Vs[0][0];          // [32][68]
  float* xqL = stL + 32 * 68;      // [32][68]
  const int ch = t >> 3;           // 0..31
  const int part = t & 7;          // 0..7
  float lsum = 0.f;
  for (int j = 0; j < 8; ++j) {
    {  // P1: coalesced x load -> xL
      const float* xp = x + (size_t)bb * CHW + (size_t)((ch << 3) + j) * HW + hwb + (part << 3);
      *(float4*)&xL[ch * 68 + (part << 3)] = *(const float4*)xp;
      *(float4*)&xL[ch * 68 + (part << 3) + 4] = *(const float4*)(xp + 4);
    }
    __syncthreads();
    {  // P2: compute (identical per-thread value/lsum chain)
      #pragma unroll
      for (int r = 0; r < 8; ++r) {
        float xq = acc[r][j];
        float xt = xL[tx * 68 + (ty << 3) + r];
        float tmp = xq - xt;
        lsum = fmaf(tmp, tmp, lsum);
        stL[tx * 68 + (ty << 3) + r] = xt + tmp;
        xqL[tx * 68 + (ty << 3) + r] = xq;
      }
    }
    __syncthreads();
    {  // P3: coalesced stores
      float* o0 = out + (size_t)bb * CHW + (size_t)((ch << 3) + j) * HW + hwb + (part << 3);
      float* o1 = o0 + PLANE;
      *(float4*)o0       = *(const float4*)&stL[ch * 68 + (part << 3)];
      *(float4*)(o0 + 4) = *(const float4*)&stL[ch * 68 + (part << 3) + 4];
      *(float4*)o1       = *(const float4*)&xqL[ch * 68 + (part << 3)];
      *(float4*)(o1 + 4) = *(const float4*)&xqL[ch * 68 + (part << 3) + 4];
    }
    __syncthreads();
  }
  red[t] = lsum;
  __syncthreads();
  for (int s = 128; s > 0; s >>= 1) {
    if (t < s) red[t] += red[t + s];
    __syncthreads();
  }
  if (t == 0) bsum[blk] = red[0];
}

// ---------------- loss ----------------
__global__ __launch_bounds__(256) void fin_kernel(const float* __restrict__ bsum,
                                                  float* __restrict__ out) {
  __shared__ float red[256];
  int t = threadIdx.x;
  red[t] = bsum[t];
  __syncthreads();
  for (int s = 128; s > 0; s >>= 1) {
    if (t < s) red[t] += red[t + s];
    __syncthreads();
  }
  if (t == 0) {
    float m = red[0] / (float)PLANE;
    out[LOSS_OFF] = m + 0.25f * m;
  }
}

extern "C" void kernel_launch(void* const* d_in, const int* in_sizes, int n_in,
                              void* d_out, int out_size, void* d_ws, size_t ws_size,
                              hipStream_t stream) {
  const float* x = (const float*)d_in[0];
  const float* ek = (const float*)d_in[1];
  const float* ev = (const float*)d_in[2];
  float* out = (float*)d_out;
  char* base = (char*)d_ws;
  unsigned short* ek_hi = (unsigned short*)(base);             //  4.0 MB
  unsigned short* x_hi  = (unsigned short*)(base + 4194304);   //  8.0 MB
  int*            idxw  = (int*)(base + 12582912);             // 64 KB
  float*          bsum  = (float*)(base + 12648448);           //  1 KB
  // smax (512 sidx x 16384 rows uints = 32 MB) lives in d_out's two output
  // planes, which out_kernel fully overwrites afterwards (same-stream ordering).
  unsigned* smax = (unsigned*)d_out;

  prep_kernel<<<2048, 256, 0, stream>>>(ek, x, ek_hi, x_hi);
  phaseA<<<8192, 256, 0, stream>>>(ek_hi, x_hi, smax);
  phaseB<<<512, 256, 0, stream>>>(x, ek, smax, idxw, out);
  out_kernel<<<256, 256, 0, stream>>>(ek, ev, x, idxw, out, bsum);
  fin_kernel<<<1, 256, 0, stream>>>(bsum, out);
}